// Round 1
// baseline (485.337 us; speedup 1.0000x reference)
//
#include <hip/hip_runtime.h>
#include <math.h>

#define B_ 4
#define C_ 2
#define F_ 512
#define W_ 1024
#define NH_ 8
#define HD_ 64
#define ROT_ 32
#define BC_ (B_*C_)

// 1/sqrt(512)  (reference scales by sqrt(h) with h = F = 512, NOT sqrt(HD))
#define SCALE_ 0.044194173824159216f

__device__ __forceinline__ float4 ld4(const float* p) { return *reinterpret_cast<const float4*>(p); }
__device__ __forceinline__ void st4(float* p, float a, float b, float c, float d) {
    *reinterpret_cast<float4*>(p) = make_float4(a, b, c, d);
}
__device__ __forceinline__ void unpack4(float4 v, float* a) { a[0]=v.x; a[1]=v.y; a[2]=v.z; a[3]=v.w; }

// out[bc][g][w] = sum_h Wm[c][g][h] * X[bc][h][w]     (M=512, N=1024, K=512)
// If ROPE: additionally write rope'd copy to Qout (Tout gets the raw values = V path).
template<bool ROPE>
__global__ __launch_bounds__(256)
void gemm_mc(const float* __restrict__ Wm, const float* __restrict__ X,
             float* __restrict__ Tout, float* __restrict__ Qout,
             const float* __restrict__ fp)
{
    __shared__ float As[16][68];   // [k][m], padded: 2-way max on stores (free)
    __shared__ float Bs[16][68];   // [k][n]
    const int tid = threadIdx.x;
    const int ty = tid >> 4, tx = tid & 15;
    const int g0 = blockIdx.x * 64, w0 = blockIdx.y * 64;
    const int bc = blockIdx.z, c = bc % C_;
    const float* A  = Wm + (size_t)c * F_ * F_;
    const float* Bx = X  + (size_t)bc * F_ * W_;

    float acc[4][4] = {};
    const int ar = tid >> 2, ac4 = (tid & 3) * 4;    // A tile: 64x16, one float4/thread
    const int br = tid >> 4, bc4 = (tid & 15) * 4;   // B tile: 16x64, one float4/thread

    for (int k0 = 0; k0 < F_; k0 += 16) {
        float4 av = ld4(&A[(g0 + ar) * F_ + k0 + ac4]);
        float4 bv = ld4(&Bx[(k0 + br) * W_ + w0 + bc4]);
        // A transposed store (scalar, 2-way alias only)
        As[ac4 + 0][ar] = av.x; As[ac4 + 1][ar] = av.y;
        As[ac4 + 2][ar] = av.z; As[ac4 + 3][ar] = av.w;
        *reinterpret_cast<float4*>(&Bs[br][bc4]) = bv;
        __syncthreads();
        #pragma unroll
        for (int k = 0; k < 16; ++k) {
            float a[4], b[4];
            unpack4(ld4(&As[k][ty * 4]), a);
            unpack4(ld4(&Bs[k][tx * 4]), b);
            #pragma unroll
            for (int i = 0; i < 4; ++i)
                #pragma unroll
                for (int j = 0; j < 4; ++j)
                    acc[i][j] = fmaf(a[i], b[j], acc[i][j]);
        }
        __syncthreads();
    }

    const int gr = g0 + ty * 4, wc = w0 + tx * 4;
    float* To = Tout + (size_t)bc * F_ * W_;
    #pragma unroll
    for (int i = 0; i < 4; ++i)
        st4(&To[(gr + i) * W_ + wc], acc[i][0], acc[i][1], acc[i][2], acc[i][3]);

    if (ROPE) {
        float* Qo = Qout + (size_t)bc * F_ * W_;
        #pragma unroll
        for (int p = 0; p < 2; ++p) {
            const int ge = gr + 2 * p;          // even row of the pair (gr % 4 == 0)
            const int d  = ge & (HD_ - 1);      // dim within head
            float qe[4], qo[4];
            if (d < ROT_) {
                const float f = fp[d >> 1];
                #pragma unroll
                for (int j = 0; j < 4; ++j) {
                    float sn, cs;
                    sincosf((float)(wc + j) * f, &sn, &cs);
                    qe[j] = acc[2*p][j]   * cs - acc[2*p+1][j] * sn;
                    qo[j] = acc[2*p+1][j] * cs + acc[2*p][j]   * sn;
                }
            } else {
                #pragma unroll
                for (int j = 0; j < 4; ++j) { qe[j] = acc[2*p][j]; qo[j] = acc[2*p+1][j]; }
            }
            st4(&Qo[ge * W_ + wc],       qe[0], qe[1], qe[2], qe[3]);
            st4(&Qo[(ge + 1) * W_ + wc], qo[0], qo[1], qo[2], qo[3]);
        }
    }
}

// Flash attention, fp32. Q == K (rope'd), V = raw projection.
// Layout of all tensors: [bc][g = n*64+d][w]   (d-major rows, w contiguous)
__global__ __launch_bounds__(256)
void attn_fp32(const float* __restrict__ Qb_, const float* __restrict__ Vb_,
               float* __restrict__ Ob_)
{
    __shared__ float Qs[64][64];   // [d][wi]
    __shared__ float Ks[64][64];   // [d][kj]
    __shared__ float Vs[64][64];   // [kj][d ^ swz(kj)]  (transposed, XOR-swizzled)
    __shared__ float Ps[64][64];   // [wi][kj]
    const int tid = threadIdx.x;
    const int ty = tid >> 4, tx = tid & 15;
    const int q0 = blockIdx.x * 64;
    const size_t hoff = ((size_t)blockIdx.z * F_ + blockIdx.y * HD_) * W_;
    const float* Qb = Qb_ + hoff;
    const float* Vb = Vb_ + hoff;

    // Q tile: 64 d-rows x 64 w-cols, one float4/thread/iter
    {
        const int d = tid >> 4, w4 = (tid & 15) * 4;
        #pragma unroll
        for (int i = 0; i < 4; ++i)
            *reinterpret_cast<float4*>(&Qs[d + i * 16][w4]) = ld4(&Qb[(d + i * 16) * W_ + q0 + w4]);
    }

    float m[4], l[4], o[4][4] = {};
    #pragma unroll
    for (int i = 0; i < 4; ++i) { m[i] = -1e30f; l[i] = 0.f; }

    for (int kt = 0; kt < 16; ++kt) {
        const int k0 = kt * 64;
        __syncthreads();   // prior PV done before overwriting Ks/Vs/Ps
        {
            const int d = tid >> 4, k4 = (tid & 15) * 4;
            #pragma unroll
            for (int i = 0; i < 4; ++i) {
                const int dr = d + i * 16;
                float4 kv = ld4(&Qb[dr * W_ + k0 + k4]);
                *reinterpret_cast<float4*>(&Ks[dr][k4]) = kv;
                float4 vv = ld4(&Vb[dr * W_ + k0 + k4]);
                float vvs[4]; unpack4(vv, vvs);
                #pragma unroll
                for (int z = 0; z < 4; ++z) {
                    const int kj = k4 + z;
                    Vs[kj][dr ^ ((kj & 7) << 2)] = vvs[z];   // 8-way worst-case, 4 stores only
                }
            }
        }
        __syncthreads();

        // S tile = Q . K^T  (reduction over d)
        float s[4][4] = {};
        for (int dd = 0; dd < 64; ++dd) {
            float qa[4], kb[4];
            unpack4(ld4(&Qs[dd][ty * 4]), qa);
            unpack4(ld4(&Ks[dd][tx * 4]), kb);
            #pragma unroll
            for (int i = 0; i < 4; ++i)
                #pragma unroll
                for (int j = 0; j < 4; ++j)
                    s[i][j] = fmaf(qa[i], kb[j], s[i][j]);
        }

        // online softmax (rows owned by the 16 tx-lanes sharing ty)
        #pragma unroll
        for (int i = 0; i < 4; ++i) {
            float mx = -1e30f;
            #pragma unroll
            for (int j = 0; j < 4; ++j) { s[i][j] *= SCALE_; mx = fmaxf(mx, s[i][j]); }
            #pragma unroll
            for (int msk = 8; msk; msk >>= 1) mx = fmaxf(mx, __shfl_xor(mx, msk));
            const float mnew = fmaxf(m[i], mx);
            const float esc  = __expf(m[i] - mnew);
            float psum = 0.f;
            #pragma unroll
            for (int j = 0; j < 4; ++j) { s[i][j] = __expf(s[i][j] - mnew); psum += s[i][j]; }
            #pragma unroll
            for (int msk = 8; msk; msk >>= 1) psum += __shfl_xor(psum, msk);
            l[i] = l[i] * esc + psum;
            m[i] = mnew;
            #pragma unroll
            for (int j = 0; j < 4; ++j) o[i][j] *= esc;
            st4(&Ps[ty * 4 + i][tx * 4], s[i][0], s[i][1], s[i][2], s[i][3]);
        }
        __syncthreads();

        // O += P . V   (reduction over kj)
        #pragma unroll 4
        for (int kj0 = 0; kj0 < 64; kj0 += 4) {
            float Pr[4][4], Vr[4][4];
            #pragma unroll
            for (int i = 0; i < 4; ++i) unpack4(ld4(&Ps[ty * 4 + i][kj0]), Pr[i]);
            #pragma unroll
            for (int z = 0; z < 4; ++z)
                unpack4(ld4(&Vs[kj0 + z][(tx * 4) ^ (((kj0 + z) & 7) << 2)]), Vr[z]);
            #pragma unroll
            for (int i = 0; i < 4; ++i)
                #pragma unroll
                for (int z = 0; z < 4; ++z)
                    #pragma unroll
                    for (int j = 0; j < 4; ++j)
                        o[i][j] = fmaf(Pr[i][z], Vr[z][j], o[i][j]);
        }
    }

    #pragma unroll
    for (int i = 0; i < 4; ++i) {
        const float inv = 1.f / l[i];
        #pragma unroll
        for (int j = 0; j < 4; ++j) o[i][j] *= inv;
    }

    // transpose O through LDS (reuse Qs) for coalesced [d][w] writes
    __syncthreads();
    #pragma unroll
    for (int i = 0; i < 4; ++i)
        #pragma unroll
        for (int j = 0; j < 4; ++j)
            Qs[tx * 4 + j][ty * 4 + i] = o[i][j];
    __syncthreads();
    float* Ob = Ob_ + hoff;
    {
        const int d = tid >> 4, w4 = (tid & 15) * 4;
        #pragma unroll
        for (int i = 0; i < 4; ++i)
            *reinterpret_cast<float4*>(&Ob[(d + i * 16) * W_ + q0 + w4]) = ld4(&Qs[d + i * 16][w4]);
    }
}

extern "C" void kernel_launch(void* const* d_in, const int* in_sizes, int n_in,
                              void* d_out, int out_size, void* d_ws, size_t ws_size,
                              hipStream_t stream) {
    const float* x  = (const float*)d_in[0];
    const float* wq = (const float*)d_in[1];
    // NOTE: reference computes q, k, v ALL from wq (wk = d_in[2], wv = d_in[3] unused).
    const float* wo = (const float*)d_in[4];
    const float* fp = (const float*)d_in[5];
    float* out = (float*)d_out;

    const size_t tensor_elems = (size_t)BC_ * F_ * W_;   // 4 Mi elems = 16 MB
    float* tbuf = (float*)d_ws;                 // raw projection (= V)
    float* qbuf = tbuf + tensor_elems;          // rope'd projection (= Q = K)
    float* abuf = qbuf + tensor_elems;          // attention output, [g][w] layout

    dim3 blk(256);
    dim3 gproj(F_ / 64, W_ / 64, BC_);          // (8, 16, 8)
    gemm_mc<true><<<gproj, blk, 0, stream>>>(wq, x, tbuf, qbuf, fp);

    dim3 gattn(W_ / 64, NH_, BC_);              // (16, 8, 8)
    attn_fp32<<<gattn, blk, 0, stream>>>(qbuf, tbuf, abuf);

    gemm_mc<false><<<gproj, blk, 0, stream>>>(wo, abuf, out, nullptr, fp);
}

// Round 2
// 198.717 us; speedup vs baseline: 2.4424x; 2.4424x over previous
//
#include <hip/hip_runtime.h>
#include <math.h>

#define B_ 4
#define C_ 2
#define F_ 512
#define W_ 1024
#define NH_ 8
#define HD_ 64
#define ROT_ 32
#define NFREQ_ 16
#define BC_ (B_*C_)

// 1/sqrt(512)
#define SCALE_ 0.044194173824159216f

typedef short bf16x8 __attribute__((ext_vector_type(8)));
typedef float f32x4  __attribute__((ext_vector_type(4)));
typedef unsigned short u16;
typedef unsigned int   u32;

__device__ __forceinline__ u16 f2bf(float f) {
    union { float f; u32 u; } v; v.f = f;
    u32 r = (v.u + 0x7fffu + ((v.u >> 16) & 1u)) >> 16;
    return (u16)r;
}
__device__ __forceinline__ float bf2f(u16 h) {
    union { u32 u; float f; } v; v.u = ((u32)h) << 16;
    return v.f;
}
__device__ __forceinline__ f32x4 mfma16(bf16x8 a, bf16x8 b, f32x4 c) {
    return __builtin_amdgcn_mfma_f32_16x16x32_bf16(a, b, c, 0, 0, 0);
}
// Read one MFMA operand fragment (8 consecutive k as bf16x8) from a swizzled
// [rows][64] u16 LDS tile. slotbase in 16B slots (0 or 4 for the two K=32 steps).
__device__ __forceinline__ bf16x8 rd8(const u16* buf, int row, int slotbase, int lane) {
    int slot = (slotbase + (lane >> 4)) ^ (row & 7);
    return *(const bf16x8*)(&buf[row * 64 + (slot << 3)]);
}

// ---------------- conversion kernels ----------------

// fp32 -> bf16 hi/lo split, same layout. n multiple of 1024.
__global__ __launch_bounds__(256)
void conv_split(const float* __restrict__ src, u16* __restrict__ hi, u16* __restrict__ lo, int n) {
    int i = (blockIdx.x * 256 + threadIdx.x) * 4;
    if (i >= n) return;
    float4 v = *(const float4*)(src + i);
    ushort4 h, l;
    h.x = f2bf(v.x); l.x = f2bf(v.x - bf2f(h.x));
    h.y = f2bf(v.y); l.y = f2bf(v.y - bf2f(h.y));
    h.z = f2bf(v.z); l.z = f2bf(v.z - bf2f(h.z));
    h.w = f2bf(v.w); l.w = f2bf(v.w - bf2f(h.w));
    *(ushort4*)(hi + i) = h;
    *(ushort4*)(lo + i) = l;
}

// x[bc][h][w] fp32 -> x_t[bc][w][h] bf16 hi/lo (transpose + split)
__global__ __launch_bounds__(256)
void conv_xt(const float* __restrict__ x, u16* __restrict__ xh, u16* __restrict__ xl) {
    __shared__ float T[64][65];
    const int t = threadIdx.x;
    const int h0 = blockIdx.x * 64, w0 = blockIdx.y * 64, bc = blockIdx.z;
    {
        const int hl = t >> 2, wc = (t & 3) * 16;
        const float* src = x + ((size_t)bc * F_ + h0 + hl) * W_ + w0 + wc;
        #pragma unroll
        for (int z = 0; z < 4; ++z)
            *(float4*)(&T[hl][wc + z * 4]) = *(const float4*)(src + z * 4);
    }
    __syncthreads();
    {
        const int wl = t >> 2, hc = (t & 3) * 16;
        u16 hv[16], lv[16];
        #pragma unroll
        for (int z = 0; z < 16; ++z) {
            float f = T[hc + z][wl];
            hv[z] = f2bf(f);
            lv[z] = f2bf(f - bf2f(hv[z]));
        }
        size_t base = ((size_t)bc * W_ + w0 + wl) * F_ + h0 + hc;
        *(uint4*)(xh + base)     = *(uint4*)(hv);
        *(uint4*)(xh + base + 8) = *(uint4*)(hv + 8);
        *(uint4*)(xl + base)     = *(uint4*)(lv);
        *(uint4*)(xl + base + 8) = *(uint4*)(lv + 8);
    }
}

// trig table: tbl[w][j] = (cos(w*fp[j]), sin(w*fp[j]))
__global__ __launch_bounds__(256)
void trig_fill(const float* __restrict__ fp, float2* __restrict__ tbl) {
    int idx = blockIdx.x * 256 + threadIdx.x;
    if (idx >= W_ * NFREQ_) return;
    int w = idx >> 4, j = idx & 15;
    float th = (float)w * fp[j];
    float s, c;
    sincosf(th, &s, &c);
    tbl[idx] = make_float2(c, s);
}

// ---------------- split-bf16 MFMA GEMM ----------------
// D[g][w] = sum_h A[g][h] * Bt[w][h]   (A = weight [C][512][512], Bt = act [bc][1024][512])
// MODE 0: proj — write V=raw bf16 [bc][g][w] and Q=rope'd bf16 q_t[bc][head][w][dd]
// MODE 1: out  — write fp32 [bc][g][w]
template<int MODE>
__global__ __launch_bounds__(256)
void gemm_split(const u16* __restrict__ Ah, const u16* __restrict__ Al,
                const u16* __restrict__ Bh, const u16* __restrict__ Bl,
                u16* __restrict__ Vout, u16* __restrict__ Qout,
                float* __restrict__ Fout, const float2* __restrict__ trig)
{
    __shared__ u16 sh[16384];            // 32 KB: As hi | As lo | Bs hi | Bs lo (each [128][32])
    u16* Ash = sh;
    u16* Asl = sh + 4096;
    u16* Bsh = sh + 8192;
    u16* Bsl = sh + 12288;

    const int tid = threadIdx.x, lane = tid & 63, wid = tid >> 6;
    const int m0 = blockIdx.x * 128, n0 = blockIdx.y * 128, bc = blockIdx.z, c = bc % C_;
    const u16* Abh = Ah + (size_t)c * F_ * F_;
    const u16* Abl = Al + (size_t)c * F_ * F_;
    const u16* Bbh = Bh + (size_t)bc * W_ * F_;
    const u16* Bbl = Bl + (size_t)bc * W_ * F_;

    f32x4 acc[4][4] = {};
    const int srow = tid >> 2, sslot = tid & 3;       // 64 rows/pass, 4 x 16B slots per row
    const int mb = (wid >> 1) * 64, nb = (wid & 1) * 64;

    for (int k0 = 0; k0 < F_; k0 += 32) {
        #pragma unroll
        for (int half = 0; half < 2; ++half) {
            const int row = srow + half * 64;
            const size_t ga = (size_t)(m0 + row) * F_ + k0 + sslot * 8;
            const size_t gb = (size_t)(n0 + row) * F_ + k0 + sslot * 8;
            uint4 vah = *(const uint4*)(Abh + ga);
            uint4 val = *(const uint4*)(Abl + ga);
            uint4 vbh = *(const uint4*)(Bbh + gb);
            uint4 vbl = *(const uint4*)(Bbl + gb);
            const int di = row * 32 + ((sslot ^ (row & 3)) << 3);
            *(uint4*)(&Ash[di]) = vah;
            *(uint4*)(&Asl[di]) = val;
            *(uint4*)(&Bsh[di]) = vbh;
            *(uint4*)(&Bsl[di]) = vbl;
        }
        __syncthreads();

        bf16x8 fah[4], fal[4];
        #pragma unroll
        for (int i = 0; i < 4; ++i) {
            const int row = mb + i * 16 + (lane & 15);
            const int idx = row * 32 + ((((lane >> 4)) ^ (row & 3)) << 3);
            fah[i] = *(const bf16x8*)(&Ash[idx]);
            fal[i] = *(const bf16x8*)(&Asl[idx]);
        }
        #pragma unroll
        for (int j = 0; j < 4; ++j) {
            const int rowb = nb + j * 16 + (lane & 15);
            const int idxb = rowb * 32 + ((((lane >> 4)) ^ (rowb & 3)) << 3);
            bf16x8 bh = *(const bf16x8*)(&Bsh[idxb]);
            bf16x8 bl = *(const bf16x8*)(&Bsl[idxb]);
            #pragma unroll
            for (int i = 0; i < 4; ++i) {
                acc[i][j] = mfma16(fah[i], bh, acc[i][j]);
                acc[i][j] = mfma16(fah[i], bl, acc[i][j]);
                acc[i][j] = mfma16(fal[i], bh, acc[i][j]);
            }
        }
        __syncthreads();
    }

    // ---- epilogue: C/D frag layout: row = (lane>>4)*4 + r, col = lane&15 ----
    #pragma unroll
    for (int i = 0; i < 4; ++i) {
        const int gr = m0 + mb + i * 16 + (lane >> 4) * 4;
        #pragma unroll
        for (int j = 0; j < 4; ++j) {
            const int wc = n0 + nb + j * 16 + (lane & 15);
            #pragma unroll
            for (int r = 0; r < 4; ++r) {
                const size_t ad = ((size_t)bc * F_ + gr + r) * W_ + wc;
                if (MODE == 1) Fout[ad] = acc[i][j][r];
                else           Vout[ad] = f2bf(acc[i][j][r]);
            }
        }
    }

    if (MODE == 0) {
        // rope in-register, transpose via per-wave LDS region, write q_t[head][w][dd]
        __syncthreads();                      // staging LDS dead now
        u16* Qt = sh + wid * 4096;            // [64 w][64 dd], swizzled
        #pragma unroll
        for (int j = 0; j < 4; ++j) {
            const int wl = j * 16 + (lane & 15);
            const int wg = n0 + nb + wl;
            #pragma unroll
            for (int i = 0; i < 4; ++i) {
                const int ddb = i * 16 + (lane >> 4) * 4;
                float q[4];
                if (i < 2) {       // dd in [0,32): rotate
                    #pragma unroll
                    for (int p = 0; p < 2; ++p) {
                        const int fidx = (ddb >> 1) + p;
                        float2 cs = trig[wg * NFREQ_ + fidx];
                        float e = acc[i][j][2 * p], o = acc[i][j][2 * p + 1];
                        q[2 * p]     = e * cs.x - o * cs.y;
                        q[2 * p + 1] = o * cs.x + e * cs.y;
                    }
                } else {
                    #pragma unroll
                    for (int r = 0; r < 4; ++r) q[r] = acc[i][j][r];
                }
                #pragma unroll
                for (int r = 0; r < 4; ++r)
                    Qt[wl * 64 + ((ddb + r) ^ ((wl & 7) << 3))] = f2bf(q[r]);
            }
        }
        // wave-local: lgkmcnt wait is handled by the compiler (same-wave LDS RAW)
        const int wl = lane;
        const int wg = n0 + nb + wl;
        const int head = (m0 + mb) >> 6;
        const size_t qbase = (((size_t)bc * NH_ + head) * W_ + wg) * 64;
        #pragma unroll
        for (int s = 0; s < 8; ++s) {
            uint4 v = *(const uint4*)(&Qt[wl * 64 + ((s ^ (wl & 7)) << 3)]);
            *(uint4*)(&Qout[qbase + s * 8]) = v;
        }
    }
}

// ---------------- MFMA flash attention (single bf16) ----------------
// Qt: [bc][head][w][64] (rope'd, = K too); Vg: [bc][g][w] raw projection.
// Writes a_t hi/lo: [bc][w][512]  (h = head*64+dd contiguous)
__global__ __launch_bounds__(256)
void attn_mfma(const u16* __restrict__ Qt, const u16* __restrict__ Vg,
               u16* __restrict__ Ah, u16* __restrict__ Al)
{
    __shared__ u16 Qs[4096], Ks[4096], Vs[4096], Ps[4096];
    const int tid = threadIdx.x, lane = tid & 63, wid = tid >> 6;
    const int q0 = blockIdx.x * 64, head = blockIdx.y, bc = blockIdx.z;
    const u16* qb = Qt + ((size_t)bc * NH_ + head) * W_ * 64;      // [w][64]
    const u16* vb = Vg + ((size_t)bc * F_ + head * HD_) * W_;      // [dd][1024]

    // stage Q tile [64 w][64 dd]
    #pragma unroll
    for (int it = 0; it < 2; ++it) {
        const int row = (tid >> 3) + it * 32, slot = tid & 7;
        uint4 v = *(const uint4*)(qb + (size_t)(q0 + row) * 64 + slot * 8);
        *(uint4*)(&Qs[row * 64 + ((slot ^ (row & 7)) << 3)]) = v;
    }

    float m[4], l[4];
    f32x4 o[4] = {};
    #pragma unroll
    for (int r = 0; r < 4; ++r) { m[r] = -1e30f; l[r] = 0.f; }
    u16* myPs = Ps + wid * 1024;   // [16 wq][64 k]

    for (int kt = 0; kt < 16; ++kt) {
        const int k0 = kt * 64;
        __syncthreads();   // prior PV reads done; Q tile visible on first iter
        #pragma unroll
        for (int it = 0; it < 2; ++it) {
            const int row = (tid >> 3) + it * 32, slot = tid & 7;
            uint4 kv = *(const uint4*)(qb + (size_t)(k0 + row) * 64 + slot * 8);
            *(uint4*)(&Ks[row * 64 + ((slot ^ (row & 7)) << 3)]) = kv;
            uint4 vv = *(const uint4*)(vb + (size_t)row * W_ + k0 + slot * 8);
            *(uint4*)(&Vs[row * 64 + ((slot ^ (row & 7)) << 3)]) = vv;
        }
        __syncthreads();

        // S = Q . K^T over d=64 (2 K=32 steps), wave's 16 q-rows x 64 k-cols
        f32x4 s[4] = {};
        #pragma unroll
        for (int ks = 0; ks < 2; ++ks) {
            bf16x8 aq = rd8(Qs, wid * 16 + (lane & 15), ks * 4, lane);
            #pragma unroll
            for (int cc = 0; cc < 4; ++cc)
                s[cc] = mfma16(aq, rd8(Ks, cc * 16 + (lane & 15), ks * 4, lane), s[cc]);
        }

        // online softmax per row r (row = (lane>>4)*4 + r)
        #pragma unroll
        for (int r = 0; r < 4; ++r) {
            float v0 = s[0][r] * SCALE_, v1 = s[1][r] * SCALE_;
            float v2 = s[2][r] * SCALE_, v3 = s[3][r] * SCALE_;
            float mx = fmaxf(fmaxf(v0, v1), fmaxf(v2, v3));
            #pragma unroll
            for (int msk = 8; msk; msk >>= 1) mx = fmaxf(mx, __shfl_xor(mx, msk));
            const float mnew = fmaxf(m[r], mx);
            const float esc = __expf(m[r] - mnew);
            float p0 = __expf(v0 - mnew), p1 = __expf(v1 - mnew);
            float p2 = __expf(v2 - mnew), p3 = __expf(v3 - mnew);
            float ps = p0 + p1 + p2 + p3;
            #pragma unroll
            for (int msk = 8; msk; msk >>= 1) ps += __shfl_xor(ps, msk);
            l[r] = l[r] * esc + ps;
            m[r] = mnew;
            #pragma unroll
            for (int dc = 0; dc < 4; ++dc) o[dc][r] *= esc;
            const int rl = (lane >> 4) * 4 + r;
            myPs[rl * 64 + ((0 * 16 + (lane & 15)) ^ ((rl & 7) << 3))] = f2bf(p0);
            myPs[rl * 64 + ((1 * 16 + (lane & 15)) ^ ((rl & 7) << 3))] = f2bf(p1);
            myPs[rl * 64 + ((2 * 16 + (lane & 15)) ^ ((rl & 7) << 3))] = f2bf(p2);
            myPs[rl * 64 + ((3 * 16 + (lane & 15)) ^ ((rl & 7) << 3))] = f2bf(p3);
        }

        // O += P . V  (wave-local P; Vs shared, barriered)
        bf16x8 pa0 = rd8(myPs, lane & 15, 0, lane);
        bf16x8 pa1 = rd8(myPs, lane & 15, 4, lane);
        #pragma unroll
        for (int dc = 0; dc < 4; ++dc) {
            o[dc] = mfma16(pa0, rd8(Vs, dc * 16 + (lane & 15), 0, lane), o[dc]);
            o[dc] = mfma16(pa1, rd8(Vs, dc * 16 + (lane & 15), 4, lane), o[dc]);
        }
    }

    // epilogue: a_t[w][head*64+dd] hi/lo
    float inv[4];
    #pragma unroll
    for (int r = 0; r < 4; ++r) inv[r] = 1.f / l[r];
    const int wqb = q0 + wid * 16 + (lane >> 4) * 4;
    #pragma unroll
    for (int dc = 0; dc < 4; ++dc) {
        const int hcol = head * HD_ + dc * 16 + (lane & 15);
        #pragma unroll
        for (int r = 0; r < 4; ++r) {
            const float val = o[dc][r] * inv[r];
            const size_t ad = ((size_t)bc * W_ + wqb + r) * F_ + hcol;
            const u16 h = f2bf(val);
            Ah[ad] = h;
            Al[ad] = f2bf(val - bf2f(h));
        }
    }
}

extern "C" void kernel_launch(void* const* d_in, const int* in_sizes, int n_in,
                              void* d_out, int out_size, void* d_ws, size_t ws_size,
                              hipStream_t stream) {
    const float* x  = (const float*)d_in[0];
    const float* wq = (const float*)d_in[1];   // q, k, v ALL use wq in the reference
    const float* wo = (const float*)d_in[4];
    const float* fp = (const float*)d_in[5];
    float* out = (float*)d_out;

    char* w8 = (char*)d_ws;
    const size_t MB = 1024 * 1024;
    u16* xh   = (u16*)(w8);                    // 8 MB  [bc][w][h] hi
    u16* xl   = (u16*)(w8 + 8 * MB);           // 8 MB
    u16* wqh  = (u16*)(w8 + 16 * MB);          // 1 MB
    u16* wql  = (u16*)(w8 + 17 * MB);
    u16* woh  = (u16*)(w8 + 18 * MB);
    u16* wol  = (u16*)(w8 + 19 * MB);
    float2* trig = (float2*)(w8 + 20 * MB);    // 128 KB
    u16* qbuf = (u16*)(w8 + 21 * MB);          // 8 MB  q_t[bc][head][w][64]
    u16* vbuf = (u16*)(w8 + 29 * MB);          // 8 MB  v[bc][g][w]
    u16* ah   = xh;                            // alias: x dead after proj GEMM
    u16* al   = xl;

    const int nw = C_ * F_ * F_;               // 524288
    conv_split<<<nw / 1024, 256, 0, stream>>>(wq, wqh, wql, nw);
    conv_split<<<nw / 1024, 256, 0, stream>>>(wo, woh, wol, nw);
    trig_fill<<<(W_ * NFREQ_) / 256, 256, 0, stream>>>(fp, trig);
    conv_xt<<<dim3(F_ / 64, W_ / 64, BC_), 256, 0, stream>>>(x, xh, xl);

    gemm_split<0><<<dim3(F_ / 128, W_ / 128, BC_), 256, 0, stream>>>(
        wqh, wql, xh, xl, vbuf, qbuf, nullptr, trig);

    attn_mfma<<<dim3(W_ / 64, NH_, BC_), 256, 0, stream>>>(qbuf, vbuf, ah, al);

    gemm_split<1><<<dim3(F_ / 128, W_ / 128, BC_), 256, 0, stream>>>(
        woh, wol, ah, al, nullptr, nullptr, out, nullptr);
}

// Round 3
// 163.801 us; speedup vs baseline: 2.9630x; 1.2132x over previous
//
#include <hip/hip_runtime.h>
#include <hip/hip_bf16.h>
#include <math.h>

#define B_ 4
#define C_ 2
#define F_ 512
#define W_ 1024
#define NH_ 8
#define HD_ 64
#define ROT_ 32
#define NFREQ_ 16
#define BC_ (B_*C_)

// sqrt( (1/sqrt(512)) * log2(e) ): folded into Q and K so p = exp2(raw mfma dot)
#define QSC_ 0.2525048f

typedef short bf16x8 __attribute__((ext_vector_type(8)));
typedef float f32x4  __attribute__((ext_vector_type(4)));
typedef float f32x16 __attribute__((ext_vector_type(16)));
typedef unsigned short u16;
typedef unsigned int   u32;

#if __has_builtin(__builtin_amdgcn_exp2f)
#define EXP2(x) __builtin_amdgcn_exp2f(x)
#else
#define EXP2(x) exp2f(x)
#endif

__device__ __forceinline__ u16 f2bf(float f) {
    union { float f; u32 u; } v; v.f = f;
    u32 r = (v.u + 0x7fffu + ((v.u >> 16) & 1u)) >> 16;
    return (u16)r;
}
__device__ __forceinline__ float bf2f(u16 h) {
    union { u32 u; float f; } v; v.u = ((u32)h) << 16;
    return v.f;
}
__device__ __forceinline__ f32x4 mfma16(bf16x8 a, bf16x8 b, f32x4 c) {
    return __builtin_amdgcn_mfma_f32_16x16x32_bf16(a, b, c, 0, 0, 0);
}
__device__ __forceinline__ f32x16 mfma32(bf16x8 a, bf16x8 b, f32x16 c) {
    return __builtin_amdgcn_mfma_f32_32x32x16_bf16(a, b, c, 0, 0, 0);
}
// async global->LDS, 16B per lane; lds base must be wave-uniform (HW adds lane*16)
__device__ __forceinline__ void gload16(const u16* g, u16* l) {
    __builtin_amdgcn_global_load_lds(
        (const __attribute__((address_space(1))) u32*)g,
        (__attribute__((address_space(3))) u32*)l, 16, 0, 0);
}
// pack two floats into one u32 of 2 bf16 (low = first)
__device__ __forceinline__ u32 pk2(float lo, float hi) {
    __hip_bfloat162 h = __float22bfloat162_rn(make_float2(lo, hi));
    union { __hip_bfloat162 b; u32 u; } cv; cv.b = h; return cv.u;
}
// v_permlane32_swap: a[32:63] <-> b[0:31]
__device__ __forceinline__ void pl32swap(u32& a, u32& b) {
    asm volatile("v_permlane32_swap_b32 %0, %1" : "+v"(a), "+v"(b));
}

// ---------------- conversion kernels ----------------

__global__ __launch_bounds__(256)
void conv_hi(const float* __restrict__ src, u16* __restrict__ hi, int n) {
    int i = (blockIdx.x * 256 + threadIdx.x) * 4;
    if (i >= n) return;
    float4 v = *(const float4*)(src + i);
    ushort4 h;
    h.x = f2bf(v.x); h.y = f2bf(v.y); h.z = f2bf(v.z); h.w = f2bf(v.w);
    *(ushort4*)(hi + i) = h;
}

__global__ __launch_bounds__(256)
void conv_split(const float* __restrict__ src, u16* __restrict__ hi, u16* __restrict__ lo, int n) {
    int i = (blockIdx.x * 256 + threadIdx.x) * 4;
    if (i >= n) return;
    float4 v = *(const float4*)(src + i);
    ushort4 h, l;
    h.x = f2bf(v.x); l.x = f2bf(v.x - bf2f(h.x));
    h.y = f2bf(v.y); l.y = f2bf(v.y - bf2f(h.y));
    h.z = f2bf(v.z); l.z = f2bf(v.z - bf2f(h.z));
    h.w = f2bf(v.w); l.w = f2bf(v.w - bf2f(h.w));
    *(ushort4*)(hi + i) = h;
    *(ushort4*)(lo + i) = l;
}

// x[bc][h][w] fp32 -> x_t[bc][w][h] bf16 (transpose, hi only)
__global__ __launch_bounds__(256)
void conv_xt(const float* __restrict__ x, u16* __restrict__ xh) {
    __shared__ float T[64][65];
    const int t = threadIdx.x;
    const int h0 = blockIdx.x * 64, w0 = blockIdx.y * 64, bc = blockIdx.z;
    {
        const int hl = t >> 2, wc = (t & 3) * 16;
        const float* src = x + ((size_t)bc * F_ + h0 + hl) * W_ + w0 + wc;
        #pragma unroll
        for (int z = 0; z < 4; ++z)
            *(float4*)(&T[hl][wc + z * 4]) = *(const float4*)(src + z * 4);
    }
    __syncthreads();
    {
        const int wl = t >> 2, hc = (t & 3) * 16;
        u16 hv[16];
        #pragma unroll
        for (int z = 0; z < 16; ++z) hv[z] = f2bf(T[hc + z][wl]);
        size_t base = ((size_t)bc * W_ + w0 + wl) * F_ + h0 + hc;
        *(uint4*)(xh + base)     = *(uint4*)(hv);
        *(uint4*)(xh + base + 8) = *(uint4*)(hv + 8);
    }
}

__global__ __launch_bounds__(256)
void trig_fill(const float* __restrict__ fp, float2* __restrict__ tbl) {
    int idx = blockIdx.x * 256 + threadIdx.x;
    if (idx >= W_ * NFREQ_) return;
    int w = idx >> 4, j = idx & 15;
    float th = (float)w * fp[j];
    float s, c;
    sincosf(th, &s, &c);
    tbl[idx] = make_float2(c, s);
}

// ---------------- MFMA GEMM (global_load_lds staging) ----------------
// D[g][w] = sum_h A[g][h] * Bt[w][h]
// MODE 0: single-pass bf16; write V (raw) + Q (rope'd, *QSC_) to q_t[bc][head][w][dd]
// MODE 1: split hi/lo 3-pass; write fp32 out
template<int MODE>
__global__ __launch_bounds__(256)
void gemm2(const u16* __restrict__ Ah_, const u16* __restrict__ Al_,
           const u16* __restrict__ Bh_, const u16* __restrict__ Bl_,
           u16* __restrict__ Vout, u16* __restrict__ Qout,
           float* __restrict__ Fout, const float2* __restrict__ trig)
{
    __shared__ u16 sh[16384];   // 32 KB
    u16* Ash = sh;
    u16* Bsh = sh + 4096;
    u16* Asl = sh + 8192;    // MODE1 only
    u16* Bsl = sh + 12288;

    const int tid = threadIdx.x, lane = tid & 63, wid = tid >> 6;
    const int m0 = blockIdx.x * 128, n0 = blockIdx.y * 128, bc = blockIdx.z, c = bc % C_;
    const u16* Abh = Ah_ + (size_t)c * F_ * F_;
    const u16* Abl = MODE ? Al_ + (size_t)c * F_ * F_ : (const u16*)nullptr;
    const u16* Bbh = Bh_ + (size_t)bc * W_ * F_;
    const u16* Bbl = MODE ? Bl_ + (size_t)bc * W_ * F_ : (const u16*)nullptr;

    f32x4 acc[4][4] = {};
    const int mb = (wid >> 1) * 64, nb = (wid & 1) * 64;
    const int r_in = lane >> 2, tsl = lane & 3;

    for (int k0 = 0; k0 < F_; k0 += 32) {
        #pragma unroll
        for (int h = 0; h < 2; ++h) {
            const int row = h * 64 + wid * 16 + r_in;
            const int ts  = tsl ^ (row & 3);
            const int lb  = (h * 64 + wid * 16) * 32;   // wave-uniform
            gload16(Abh + (size_t)(m0 + row) * F_ + k0 + ts * 8, Ash + lb);
            gload16(Bbh + (size_t)(n0 + row) * F_ + k0 + ts * 8, Bsh + lb);
            if (MODE) {
                gload16(Abl + (size_t)(m0 + row) * F_ + k0 + ts * 8, Asl + lb);
                gload16(Bbl + (size_t)(n0 + row) * F_ + k0 + ts * 8, Bsl + lb);
            }
        }
        __syncthreads();

        bf16x8 fah[4], fal[4];
        #pragma unroll
        for (int i = 0; i < 4; ++i) {
            const int row = mb + i * 16 + (lane & 15);
            const int idx = row * 32 + (((lane >> 4) ^ (row & 3)) << 3);
            fah[i] = *(const bf16x8*)(&Ash[idx]);
            if (MODE) fal[i] = *(const bf16x8*)(&Asl[idx]);
        }
        #pragma unroll
        for (int j = 0; j < 4; ++j) {
            const int rowb = nb + j * 16 + (lane & 15);
            const int idxb = rowb * 32 + (((lane >> 4) ^ (rowb & 3)) << 3);
            bf16x8 bh = *(const bf16x8*)(&Bsh[idxb]);
            #pragma unroll
            for (int i = 0; i < 4; ++i)
                acc[i][j] = mfma16(fah[i], bh, acc[i][j]);
            if (MODE) {
                bf16x8 bl = *(const bf16x8*)(&Bsl[idxb]);
                #pragma unroll
                for (int i = 0; i < 4; ++i) {
                    acc[i][j] = mfma16(fah[i], bl, acc[i][j]);
                    acc[i][j] = mfma16(fal[i], bh, acc[i][j]);
                }
            }
        }
        __syncthreads();
    }

    // C/D frag: row = (lane>>4)*4 + r, col = lane&15
    #pragma unroll
    for (int i = 0; i < 4; ++i) {
        const int gr = m0 + mb + i * 16 + (lane >> 4) * 4;
        #pragma unroll
        for (int j = 0; j < 4; ++j) {
            const int wc = n0 + nb + j * 16 + (lane & 15);
            #pragma unroll
            for (int r = 0; r < 4; ++r) {
                const size_t ad = ((size_t)bc * F_ + gr + r) * W_ + wc;
                if (MODE == 1) Fout[ad] = acc[i][j][r];
                else           Vout[ad] = f2bf(acc[i][j][r]);
            }
        }
    }

    if (MODE == 0) {
        __syncthreads();                      // staging LDS dead
        u16* Qt = sh + wid * 4096;            // per-wave [64 w][64 dd], swizzled
        #pragma unroll
        for (int j = 0; j < 4; ++j) {
            const int wl = j * 16 + (lane & 15);
            const int wg = n0 + nb + wl;
            #pragma unroll
            for (int i = 0; i < 4; ++i) {
                const int ddb = i * 16 + (lane >> 4) * 4;
                float q[4];
                if (i < 2) {       // dd < 32: rotate
                    #pragma unroll
                    for (int p = 0; p < 2; ++p) {
                        const int fidx = (ddb >> 1) + p;
                        float2 cs = trig[wg * NFREQ_ + fidx];
                        float e = acc[i][j][2 * p], o = acc[i][j][2 * p + 1];
                        q[2 * p]     = (e * cs.x - o * cs.y) * QSC_;
                        q[2 * p + 1] = (o * cs.x + e * cs.y) * QSC_;
                    }
                } else {
                    #pragma unroll
                    for (int r = 0; r < 4; ++r) q[r] = acc[i][j][r] * QSC_;
                }
                #pragma unroll
                for (int r = 0; r < 4; ++r)
                    Qt[wl * 64 + ((ddb + r) ^ ((wl & 7) << 3))] = f2bf(q[r]);
            }
        }
        const int wl = lane;
        const int wg = n0 + nb + wl;
        const int head = (m0 + mb) >> 6;
        const size_t qbase = (((size_t)bc * NH_ + head) * W_ + wg) * 64;
        #pragma unroll
        for (int s = 0; s < 8; ++s) {
            uint4 v = *(const uint4*)(&Qt[wl * 64 + ((s ^ (wl & 7)) << 3)]);
            *(uint4*)(&Qout[qbase + s * 8]) = v;
        }
    }
}

// ---------------- transposed 32x32-MFMA flash attention ----------------
// Qt: [bc][head][w][64] (rope'd, *QSC_; serves as both Q and K). Vg: [bc][g][w] raw.
// S^T = mfma32(K, Q^T): C col=lane&31 -> q, rows -> k.  p = exp2(s), no max-sub.
// O^T = mfma32(V^T, P^T) with P^T frags built via cvt_pk + permlane32_swap.
// Writes a_t hi/lo: [bc][w][512]
__global__ __launch_bounds__(256)
void attn2(const u16* __restrict__ Qt, const u16* __restrict__ Vg,
           u16* __restrict__ Ah, u16* __restrict__ Al)
{
    __shared__ u16 Ks[4096];   // [64 k][64 d], 16B-slot swizzle: slot ^ (row&7)
    __shared__ u16 Vs[4096];   // [64 d][64 k], same swizzle
    const int tid = threadIdx.x, lane = tid & 63, wid = tid >> 6;
    const int q0 = blockIdx.x * 128, head = blockIdx.y, bc = blockIdx.z;
    const u16* qb = Qt + ((size_t)bc * NH_ + head) * W_ * 64;
    const u16* vb = Vg + ((size_t)bc * F_ + head * HD_) * W_;

    const int qcol = lane & 31, hi = lane >> 5;

    // hoisted Q B-frags: lane&31 = q col, d = ks*16 + hi*8 + j
    bf16x8 qf[4];
    {
        const u16* qrow = qb + (size_t)(q0 + wid * 32 + qcol) * 64 + hi * 8;
        #pragma unroll
        for (int ks = 0; ks < 4; ++ks)
            qf[ks] = *(const bf16x8*)(qrow + ks * 16);
    }

    f32x16 o0, o1;
    #pragma unroll
    for (int i = 0; i < 16; ++i) { o0[i] = 0.f; o1[i] = 0.f; }
    float lsum = 0.f;

    const int srow = lane >> 3, st = lane & 7;

    for (int kt = 0; kt < 16; ++kt) {
        const int k0 = kt * 64;
        // stage K tile [64 k][64 d] and V tile [64 d][64 k]
        #pragma unroll
        for (int p = 0; p < 2; ++p) {
            const int rb = wid * 16 + p * 8;
            const int r  = rb + srow;
            const int ts = st ^ (r & 7);
            gload16(qb + (size_t)(k0 + r) * 64 + ts * 8, Ks + rb * 64);
            gload16(vb + (size_t)r * W_ + k0 + ts * 8,   Vs + rb * 64);
        }
        __syncthreads();

        // S^T = K . Q^T over d (4 K=16 steps), two 32-k blocks
        f32x16 s0, s1;
        #pragma unroll
        for (int i = 0; i < 16; ++i) { s0[i] = 0.f; s1[i] = 0.f; }
        #pragma unroll
        for (int ks = 0; ks < 4; ++ks) {
            const int sl = ks * 2 + hi;
            const int kA = qcol;
            const int kB = 32 + qcol;
            bf16x8 kf0 = *(const bf16x8*)(Ks + kA * 64 + ((sl ^ (kA & 7)) << 3));
            bf16x8 kf1 = *(const bf16x8*)(Ks + kB * 64 + ((sl ^ (kB & 7)) << 3));
            s0 = mfma32(kf0, qf[ks], s0);
            s1 = mfma32(kf1, qf[ks], s1);
        }

        // p = exp2(s) (scale folded into Q/K); accumulate denominator
        float p0[16], p1[16];
        #pragma unroll
        for (int i = 0; i < 16; ++i) { p0[i] = EXP2(s0[i]); p1[i] = EXP2(s1[i]); }
        float part = 0.f;
        #pragma unroll
        for (int i = 0; i < 16; ++i) part += p0[i] + p1[i];
        lsum += part;

        // build 4 P^T B-frags (k 0..63) in-register
        bf16x8 pf[4];
        #pragma unroll
        for (int kb = 0; kb < 2; ++kb) {
            const float* pp = kb ? p1 : p0;
            #pragma unroll
            for (int f = 0; f < 2; ++f) {
                u32 a1 = pk2(pp[f*8+0], pp[f*8+1]);
                u32 a2 = pk2(pp[f*8+2], pp[f*8+3]);
                u32 b1 = pk2(pp[f*8+4], pp[f*8+5]);
                u32 b2 = pk2(pp[f*8+6], pp[f*8+7]);
                pl32swap(a1, b1);
                pl32swap(a2, b2);
                union { u32 w[4]; bf16x8 v; } u;
                u.w[0] = a1; u.w[1] = a2; u.w[2] = b1; u.w[3] = b2;
                pf[kb * 2 + f] = u.v;
            }
        }

        // O^T += V^T . P^T  (A = V^T from Vs [d][k], B = pf)
        #pragma unroll
        for (int ks2 = 0; ks2 < 4; ++ks2) {
            const int sl = ks2 * 2 + hi;
            const int d0r = qcol;
            const int d1r = 32 + qcol;
            bf16x8 vf0 = *(const bf16x8*)(Vs + d0r * 64 + ((sl ^ (d0r & 7)) << 3));
            bf16x8 vf1 = *(const bf16x8*)(Vs + d1r * 64 + ((sl ^ (d1r & 7)) << 3));
            o0 = mfma32(vf0, pf[ks2], o0);
            o1 = mfma32(vf1, pf[ks2], o1);
        }
        __syncthreads();
    }

    lsum += __shfl_xor(lsum, 32);
    const float inv = 1.f / lsum;

    const int wrow = q0 + wid * 32 + qcol;
    const size_t rowbase = ((size_t)bc * W_ + wrow) * F_ + head * HD_;
    #pragma unroll
    for (int dblk = 0; dblk < 2; ++dblk) {
        const f32x16 ov = dblk ? o1 : o0;
        const int coloff = dblk * 32;
        #pragma unroll
        for (int pr = 0; pr < 8; ++pr) {      // reg pair (2pr, 2pr+1) -> d rows (drow, drow+1)
            const float v1 = ov[2 * pr]     * inv;
            const float v2 = ov[2 * pr + 1] * inv;
            const int drow = ((2 * pr) & 3) + 8 * (pr >> 1) + 4 * hi;
            const u16 h1 = f2bf(v1), h2 = f2bf(v2);
            const u16 l1 = f2bf(v1 - bf2f(h1)), l2 = f2bf(v2 - bf2f(h2));
            *(u32*)(Ah + rowbase + coloff + drow) = (u32)h1 | ((u32)h2 << 16);
            *(u32*)(Al + rowbase + coloff + drow) = (u32)l1 | ((u32)l2 << 16);
        }
    }
}

extern "C" void kernel_launch(void* const* d_in, const int* in_sizes, int n_in,
                              void* d_out, int out_size, void* d_ws, size_t ws_size,
                              hipStream_t stream) {
    const float* x  = (const float*)d_in[0];
    const float* wq = (const float*)d_in[1];   // reference: q, k, v ALL from wq
    const float* wo = (const float*)d_in[4];
    const float* fp = (const float*)d_in[5];
    float* out = (float*)d_out;

    char* w8 = (char*)d_ws;
    const size_t MB = 1024 * 1024;
    u16* xh   = (u16*)(w8);                    // 8 MB  x_t[bc][w][h] bf16
    u16* wqh  = (u16*)(w8 + 8 * MB);           // 1 MB
    u16* woh  = (u16*)(w8 + 9 * MB);           // 1 MB
    u16* wol  = (u16*)(w8 + 10 * MB);          // 1 MB
    float2* trig = (float2*)(w8 + 11 * MB);    // 128 KB
    u16* qbuf = (u16*)(w8 + 12 * MB);          // 8 MB  q_t[bc][head][w][64]
    u16* vbuf = (u16*)(w8 + 20 * MB);          // 8 MB  v[bc][g][w]
    u16* al   = (u16*)(w8 + 28 * MB);          // 8 MB  a_t lo
    u16* ah   = xh;                            // alias: x_t dead after proj GEMM

    const int nw = C_ * F_ * F_;               // 524288
    conv_hi<<<nw / 1024, 256, 0, stream>>>(wq, wqh, nw);
    conv_split<<<nw / 1024, 256, 0, stream>>>(wo, woh, wol, nw);
    trig_fill<<<(W_ * NFREQ_) / 256, 256, 0, stream>>>(fp, trig);
    conv_xt<<<dim3(F_ / 64, W_ / 64, BC_), 256, 0, stream>>>(x, xh);

    gemm2<0><<<dim3(F_ / 128, W_ / 128, BC_), 256, 0, stream>>>(
        wqh, nullptr, xh, nullptr, vbuf, qbuf, nullptr, trig);

    attn2<<<dim3(W_ / 128, NH_, BC_), 256, 0, stream>>>(qbuf, vbuf, ah, al);

    gemm2<1><<<dim3(F_ / 128, W_ / 128, BC_), 256, 0, stream>>>(
        woh, wol, ah, al, nullptr, nullptr, out, nullptr);
}

// Round 5
// 148.598 us; speedup vs baseline: 3.2661x; 1.1023x over previous
//
#include <hip/hip_runtime.h>
#include <hip/hip_bf16.h>
#include <math.h>

#define B_ 4
#define C_ 2
#define F_ 512
#define W_ 1024
#define NH_ 8
#define HD_ 64
#define ROT_ 32
#define NFREQ_ 16
#define BC_ (B_*C_)

// sqrt( (1/sqrt(512)) * log2(e) ): folded into Q and K so p = exp2(raw mfma dot)
#define QSC_ 0.2525048f

typedef short bf16x8 __attribute__((ext_vector_type(8)));
typedef float f32x4  __attribute__((ext_vector_type(4)));
typedef float f32x16 __attribute__((ext_vector_type(16)));
typedef unsigned short u16;
typedef unsigned int   u32;

#if __has_builtin(__builtin_amdgcn_exp2f)
#define EXP2(x) __builtin_amdgcn_exp2f(x)
#else
#define EXP2(x) exp2f(x)
#endif

// Explicit LDS-DMA drain: __syncthreads()' implicit vmcnt drain is NOT
// guaranteed to cover global_load_lds when the consumer ds_reads target a
// different LDS buffer (dbuf) — the round-4 race. Always drain before the
// publishing barrier.
#define VDRAIN() asm volatile("s_waitcnt vmcnt(0)" ::: "memory")

__device__ __forceinline__ u16 f2bf(float f) {
    union { float f; u32 u; } v; v.f = f;
    u32 r = (v.u + 0x7fffu + ((v.u >> 16) & 1u)) >> 16;
    return (u16)r;
}
__device__ __forceinline__ float bf2f(u16 h) {
    union { u32 u; float f; } v; v.u = ((u32)h) << 16;
    return v.f;
}
__device__ __forceinline__ f32x4 mfma16(bf16x8 a, bf16x8 b, f32x4 c) {
    return __builtin_amdgcn_mfma_f32_16x16x32_bf16(a, b, c, 0, 0, 0);
}
__device__ __forceinline__ f32x16 mfma32(bf16x8 a, bf16x8 b, f32x16 c) {
    return __builtin_amdgcn_mfma_f32_32x32x16_bf16(a, b, c, 0, 0, 0);
}
// async global->LDS, 16B per lane; lds base must be wave-uniform (HW adds lane*16)
__device__ __forceinline__ void gload16(const u16* g, u16* l) {
    __builtin_amdgcn_global_load_lds(
        (const __attribute__((address_space(1))) u32*)g,
        (__attribute__((address_space(3))) u32*)l, 16, 0, 0);
}
__device__ __forceinline__ u32 pk2(float lo, float hi) {
    __hip_bfloat162 h = __float22bfloat162_rn(make_float2(lo, hi));
    union { __hip_bfloat162 b; u32 u; } cv; cv.b = h; return cv.u;
}
// v_permlane32_swap: a[32:63] <-> b[0:31]
__device__ __forceinline__ void pl32swap(u32& a, u32& b) {
    asm volatile("v_permlane32_swap_b32 %0, %1" : "+v"(a), "+v"(b));
}

// ---------------- fused prep: wq->bf16, wo->hi/lo split, trig table ----------------
__global__ __launch_bounds__(256)
void prep(const float* __restrict__ wq, const float* __restrict__ wo,
          const float* __restrict__ fp,
          u16* __restrict__ wqh, u16* __restrict__ woh, u16* __restrict__ wol,
          float2* __restrict__ trig)
{
    const int b = blockIdx.x, t = threadIdx.x;
    if (b < 512) {                       // wq -> bf16 hi only
        int i = (b * 256 + t) * 4;
        float4 v = *(const float4*)(wq + i);
        ushort4 h;
        h.x = f2bf(v.x); h.y = f2bf(v.y); h.z = f2bf(v.z); h.w = f2bf(v.w);
        *(ushort4*)(wqh + i) = h;
    } else if (b < 1024) {               // wo -> hi/lo split
        int i = ((b - 512) * 256 + t) * 4;
        float4 v = *(const float4*)(wo + i);
        ushort4 h, l;
        h.x = f2bf(v.x); l.x = f2bf(v.x - bf2f(h.x));
        h.y = f2bf(v.y); l.y = f2bf(v.y - bf2f(h.y));
        h.z = f2bf(v.z); l.z = f2bf(v.z - bf2f(h.z));
        h.w = f2bf(v.w); l.w = f2bf(v.w - bf2f(h.w));
        *(ushort4*)(woh + i) = h;
        *(ushort4*)(wol + i) = l;
    } else {                             // trig table: 64 blocks x 256 = 16384 entries
        int idx = (b - 1024) * 256 + t;
        int w = idx >> 4, j = idx & 15;
        float th = (float)w * fp[j];
        float s, c;
        sincosf(th, &s, &c);
        trig[idx] = make_float2(c, s);
    }
}

// x[bc][h][w] fp32 -> x_t[bc][w][h] bf16 (transpose)
__global__ __launch_bounds__(256)
void conv_xt(const float* __restrict__ x, u16* __restrict__ xh) {
    __shared__ float T[64][65];
    const int t = threadIdx.x;
    const int h0 = blockIdx.x * 64, w0 = blockIdx.y * 64, bc = blockIdx.z;
    {
        const int hl = t >> 2, wc = (t & 3) * 16;
        const float* src = x + ((size_t)bc * F_ + h0 + hl) * W_ + w0 + wc;
        #pragma unroll
        for (int z = 0; z < 4; ++z)
            *(float4*)(&T[hl][wc + z * 4]) = *(const float4*)(src + z * 4);
    }
    __syncthreads();
    {
        const int wl = t >> 2, hc = (t & 3) * 16;
        u16 hv[16];
        #pragma unroll
        for (int z = 0; z < 16; ++z) hv[z] = f2bf(T[hc + z][wl]);
        size_t base = ((size_t)bc * W_ + w0 + wl) * F_ + h0 + hc;
        *(uint4*)(xh + base)     = *(uint4*)(hv);
        *(uint4*)(xh + base + 8) = *(uint4*)(hv + 8);
    }
}

// ---------------- MFMA GEMM, double-buffered prefetch (T3, explicit drains) ----------------
// D[g][w] = sum_h A[g][h] * Bt[w][h]
// MODE 0: single-pass bf16; write V (raw) + Q (rope'd, *QSC_) to q_t[bc][head][w][dd]
// MODE 1: split hi/lo 3-pass; write fp32 out
// LDS row = 32 u16 (64B); swizzle slot ^= (row>>1)&3 -> 2 lanes/bank on frag reads (free)
template<int MODE>
__global__ __launch_bounds__(256)
void gemm3(const u16* __restrict__ Ah_, const u16* __restrict__ Al_,
           const u16* __restrict__ Bh_, const u16* __restrict__ Bl_,
           u16* __restrict__ Vout, u16* __restrict__ Qout,
           float* __restrict__ Fout, const float2* __restrict__ trig)
{
    constexpr int BUFS = MODE ? 16384 : 8192;     // u16 per buffer set
    __shared__ u16 sh[2 * BUFS];                  // MODE1: 64KB, MODE0: 32KB

    const int tid = threadIdx.x, lane = tid & 63, wid = tid >> 6;
    const int m0 = blockIdx.x * 128, n0 = blockIdx.y * 128, bc = blockIdx.z, c = bc % C_;
    const u16* Abh = Ah_ + (size_t)c * F_ * F_;
    const u16* Abl = MODE ? (Al_ + (size_t)c * F_ * F_) : (const u16*)nullptr;
    const u16* Bbh = Bh_ + (size_t)bc * W_ * F_;
    const u16* Bbl = MODE ? (Bl_ + (size_t)bc * W_ * F_) : (const u16*)nullptr;

    f32x4 acc[4][4] = {};
    const int mb = (wid >> 1) * 64, nb = (wid & 1) * 64;
    const int r_in = lane >> 2, tsl = lane & 3;

    auto STAGE = [&](int k0, int buf) {
        u16* base = sh + buf * BUFS;
        #pragma unroll
        for (int h = 0; h < 2; ++h) {
            const int row = h * 64 + wid * 16 + r_in;
            const int ts  = tsl ^ ((row >> 1) & 3);
            const int lb  = (h * 64 + wid * 16) * 32;   // wave-uniform LDS base
            gload16(Abh + (size_t)(m0 + row) * F_ + k0 + ts * 8, base + lb);
            gload16(Bbh + (size_t)(n0 + row) * F_ + k0 + ts * 8, base + 4096 + lb);
            if constexpr (MODE) {
                gload16(Abl + (size_t)(m0 + row) * F_ + k0 + ts * 8, base + 8192 + lb);
                gload16(Bbl + (size_t)(n0 + row) * F_ + k0 + ts * 8, base + 12288 + lb);
            }
        }
    };

    STAGE(0, 0);
    VDRAIN();                // own DMA landed in buf 0
    __syncthreads();         // publish buf 0
    int cur = 0;
    for (int kt = 0; kt < 16; ++kt) {
        if (kt < 15) STAGE((kt + 1) * 32, cur ^ 1);   // flies during compute below
        const u16* Ash = sh + cur * BUFS;
        const u16* Bsh = Ash + 4096;
        const u16* Asl = MODE ? Ash + 8192  : Ash;
        const u16* Bsl = MODE ? Ash + 12288 : Ash;

        bf16x8 fah[4], fal[4];
        #pragma unroll
        for (int i = 0; i < 4; ++i) {
            const int row = mb + i * 16 + (lane & 15);
            const int idx = row * 32 + (((lane >> 4) ^ ((row >> 1) & 3)) << 3);
            fah[i] = *(const bf16x8*)(&Ash[idx]);
            if constexpr (MODE) fal[i] = *(const bf16x8*)(&Asl[idx]);
        }
        #pragma unroll
        for (int j = 0; j < 4; ++j) {
            const int rowb = nb + j * 16 + (lane & 15);
            const int idxb = rowb * 32 + (((lane >> 4) ^ ((rowb >> 1) & 3)) << 3);
            bf16x8 bh = *(const bf16x8*)(&Bsh[idxb]);
            #pragma unroll
            for (int i = 0; i < 4; ++i)
                acc[i][j] = mfma16(fah[i], bh, acc[i][j]);
            if constexpr (MODE) {
                bf16x8 bl = *(const bf16x8*)(&Bsl[idxb]);
                #pragma unroll
                for (int i = 0; i < 4; ++i) {
                    acc[i][j] = mfma16(fah[i], bl, acc[i][j]);
                    acc[i][j] = mfma16(fal[i], bh, acc[i][j]);
                }
            }
        }
        VDRAIN();            // own prefetch DMA landed before buffer becomes readable
        __syncthreads();     // publish cur^1; all reads of cur done
        cur ^= 1;
    }

    // C/D frag: row = (lane>>4)*4 + r, col = lane&15
    #pragma unroll
    for (int i = 0; i < 4; ++i) {
        const int gr = m0 + mb + i * 16 + (lane >> 4) * 4;
        #pragma unroll
        for (int j = 0; j < 4; ++j) {
            const int wc = n0 + nb + j * 16 + (lane & 15);
            #pragma unroll
            for (int r = 0; r < 4; ++r) {
                const size_t ad = ((size_t)bc * F_ + gr + r) * W_ + wc;
                if constexpr (MODE == 1) Fout[ad] = acc[i][j][r];
                else                     Vout[ad] = f2bf(acc[i][j][r]);
            }
        }
    }

    if constexpr (MODE == 0) {
        __syncthreads();                      // staging LDS dead (all DMAs drained in-loop)
        u16* Qt = sh + wid * 4096;            // per-wave [64 w][64 dd], swizzled
        #pragma unroll
        for (int j = 0; j < 4; ++j) {
            const int wl = j * 16 + (lane & 15);
            const int wg = n0 + nb + wl;
            #pragma unroll
            for (int i = 0; i < 4; ++i) {
                const int ddb = i * 16 + (lane >> 4) * 4;
                float q[4];
                if (i < 2) {       // dd < 32: rotate
                    #pragma unroll
                    for (int p = 0; p < 2; ++p) {
                        const int fidx = (ddb >> 1) + p;
                        float2 cs = trig[wg * NFREQ_ + fidx];
                        float e = acc[i][j][2 * p], o = acc[i][j][2 * p + 1];
                        q[2 * p]     = (e * cs.x - o * cs.y) * QSC_;
                        q[2 * p + 1] = (o * cs.x + e * cs.y) * QSC_;
                    }
                } else {
                    #pragma unroll
                    for (int r = 0; r < 4; ++r) q[r] = acc[i][j][r] * QSC_;
                }
                #pragma unroll
                for (int r = 0; r < 4; ++r)
                    Qt[wl * 64 + ((ddb + r) ^ ((wl & 7) << 3))] = f2bf(q[r]);
            }
        }
        const int wl = lane;
        const int wg = n0 + nb + wl;
        const int head = (m0 + mb) >> 6;
        const size_t qbase = (((size_t)bc * NH_ + head) * W_ + wg) * 64;
        #pragma unroll
        for (int s = 0; s < 8; ++s) {
            uint4 v = *(const uint4*)(&Qt[wl * 64 + ((s ^ (wl & 7)) << 3)]);
            *(uint4*)(&Qout[qbase + s * 8]) = v;
        }
    }
}

// ---------------- transposed 32x32-MFMA flash attention, dbuf prefetch ----------------
// Qt: [bc][head][w][64] (rope'd, *QSC_; both Q and K). Vg: [bc][g][w] raw.
// S^T = mfma32(K, Q^T); p = exp2(s) (no max-sub, logits bounded ~2);
// O^T = mfma32(V^T, P^T), P^T frags built via cvt_pk + permlane32_swap. No P in LDS.
__global__ __launch_bounds__(256)
void attn3(const u16* __restrict__ Qt, const u16* __restrict__ Vg,
           u16* __restrict__ Ah, u16* __restrict__ Al)
{
    __shared__ u16 sh[16384];      // Ks0|Vs0|Ks1|Vs1, each [64][64] u16, slot^(row&7) swizzle
    const int tid = threadIdx.x, lane = tid & 63, wid = tid >> 6;
    const int q0 = blockIdx.x * 128, head = blockIdx.y, bc = blockIdx.z;
    const u16* qb = Qt + ((size_t)bc * NH_ + head) * W_ * 64;
    const u16* vb = Vg + ((size_t)bc * F_ + head * HD_) * W_;

    const int qcol = lane & 31, hi = lane >> 5;
    const int srow = lane >> 3, st = lane & 7;

    // hoisted Q B-frags: lane&31 = q col, d = ks*16 + hi*8 + j
    bf16x8 qf[4];
    {
        const u16* qrow = qb + (size_t)(q0 + wid * 32 + qcol) * 64 + hi * 8;
        #pragma unroll
        for (int ks = 0; ks < 4; ++ks)
            qf[ks] = *(const bf16x8*)(qrow + ks * 16);
    }

    f32x16 o0, o1;
    #pragma unroll
    for (int i = 0; i < 16; ++i) { o0[i] = 0.f; o1[i] = 0.f; }
    float lsum = 0.f;

    auto STAGE = [&](int kt, int buf) {
        const int k0 = kt * 64;
        u16* Ksb = sh + buf * 8192;
        u16* Vsb = Ksb + 4096;
        #pragma unroll
        for (int p = 0; p < 2; ++p) {
            const int rb = wid * 16 + p * 8;          // wave-uniform
            const int r  = rb + srow;
            const int ts = st ^ (r & 7);
            gload16(qb + (size_t)(k0 + r) * 64 + ts * 8, Ksb + rb * 64);
            gload16(vb + (size_t)r * W_ + k0 + ts * 8,   Vsb + rb * 64);
        }
    };

    STAGE(0, 0);
    VDRAIN();                 // own DMA (and qf loads) landed
    __syncthreads();          // publish buf 0
    int cur = 0;
    for (int kt = 0; kt < 16; ++kt) {
        if (kt < 15) STAGE(kt + 1, cur ^ 1);   // flies during compute below
        const u16* Ks = sh + cur * 8192;
        const u16* Vs = Ks + 4096;

        // S^T = K . Q^T over d (4 K=16 steps), two 32-k blocks
        f32x16 s0, s1;
        #pragma unroll
        for (int i = 0; i < 16; ++i) { s0[i] = 0.f; s1[i] = 0.f; }
        #pragma unroll
        for (int ks = 0; ks < 4; ++ks) {
            const int sl = ks * 2 + hi;
            const int kA = qcol;
            const int kB = 32 + qcol;
            bf16x8 kf0 = *(const bf16x8*)(Ks + kA * 64 + ((sl ^ (kA & 7)) << 3));
            bf16x8 kf1 = *(const bf16x8*)(Ks + kB * 64 + ((sl ^ (kB & 7)) << 3));
            s0 = mfma32(kf0, qf[ks], s0);
            s1 = mfma32(kf1, qf[ks], s1);
        }

        // p = exp2(s); accumulate denominator
        float p0[16], p1[16];
        #pragma unroll
        for (int i = 0; i < 16; ++i) { p0[i] = EXP2(s0[i]); p1[i] = EXP2(s1[i]); }
        float part = 0.f;
        #pragma unroll
        for (int i = 0; i < 16; ++i) part += p0[i] + p1[i];
        lsum += part;

        // 4 P^T B-frags in-register (cvt_pk + permlane32_swap)
        bf16x8 pf[4];
        #pragma unroll
        for (int kb = 0; kb < 2; ++kb) {
            const float* pp = kb ? p1 : p0;
            #pragma unroll
            for (int f = 0; f < 2; ++f) {
                u32 a1 = pk2(pp[f*8+0], pp[f*8+1]);
                u32 a2 = pk2(pp[f*8+2], pp[f*8+3]);
                u32 b1 = pk2(pp[f*8+4], pp[f*8+5]);
                u32 b2 = pk2(pp[f*8+6], pp[f*8+7]);
                pl32swap(a1, b1);
                pl32swap(a2, b2);
                union { u32 w[4]; bf16x8 v; } u;
                u.w[0] = a1; u.w[1] = a2; u.w[2] = b1; u.w[3] = b2;
                pf[kb * 2 + f] = u.v;
            }
        }

        // O^T += V^T . P^T
        #pragma unroll
        for (int ks2 = 0; ks2 < 4; ++ks2) {
            const int sl = ks2 * 2 + hi;
            const int d0r = qcol;
            const int d1r = 32 + qcol;
            bf16x8 vf0 = *(const bf16x8*)(Vs + d0r * 64 + ((sl ^ (d0r & 7)) << 3));
            bf16x8 vf1 = *(const bf16x8*)(Vs + d1r * 64 + ((sl ^ (d1r & 7)) << 3));
            o0 = mfma32(vf0, pf[ks2], o0);
            o1 = mfma32(vf1, pf[ks2], o1);
        }
        VDRAIN();            // own prefetch DMA landed before buffer becomes readable
        __syncthreads();     // publish cur^1; all reads of cur done
        cur ^= 1;
    }

    lsum += __shfl_xor(lsum, 32);
    const float inv = 1.f / lsum;

    const int wrow = q0 + wid * 32 + qcol;
    const size_t rowbase = ((size_t)bc * W_ + wrow) * F_ + head * HD_;
    #pragma unroll
    for (int dblk = 0; dblk < 2; ++dblk) {
        const f32x16 ov = dblk ? o1 : o0;
        const int coloff = dblk * 32;
        #pragma unroll
        for (int pr = 0; pr < 8; ++pr) {      // reg pair (2pr,2pr+1) -> d rows (drow,drow+1)
            const float v1 = ov[2 * pr]     * inv;
            const float v2 = ov[2 * pr + 1] * inv;
            const int drow = ((2 * pr) & 3) + 8 * (pr >> 1) + 4 * hi;
            const u16 h1 = f2bf(v1), h2 = f2bf(v2);
            const u16 l1 = f2bf(v1 - bf2f(h1)), l2 = f2bf(v2 - bf2f(h2));
            *(u32*)(Ah + rowbase + coloff + drow) = (u32)h1 | ((u32)h2 << 16);
            *(u32*)(Al + rowbase + coloff + drow) = (u32)l1 | ((u32)l2 << 16);
        }
    }
}

extern "C" void kernel_launch(void* const* d_in, const int* in_sizes, int n_in,
                              void* d_out, int out_size, void* d_ws, size_t ws_size,
                              hipStream_t stream) {
    const float* x  = (const float*)d_in[0];
    const float* wq = (const float*)d_in[1];   // reference: q, k, v ALL from wq
    const float* wo = (const float*)d_in[4];
    const float* fp = (const float*)d_in[5];
    float* out = (float*)d_out;

    char* w8 = (char*)d_ws;
    const size_t MB = 1024 * 1024;
    u16* xh   = (u16*)(w8);                    // 8 MB  x_t[bc][w][h] bf16
    u16* wqh  = (u16*)(w8 + 8 * MB);           // 1 MB
    u16* woh  = (u16*)(w8 + 9 * MB);           // 1 MB
    u16* wol  = (u16*)(w8 + 10 * MB);          // 1 MB
    float2* trig = (float2*)(w8 + 11 * MB);    // 128 KB
    u16* qbuf = (u16*)(w8 + 12 * MB);          // 8 MB  q_t[bc][head][w][64]
    u16* vbuf = (u16*)(w8 + 20 * MB);          // 8 MB  v[bc][g][w]
    u16* al   = (u16*)(w8 + 28 * MB);          // 8 MB  a_t lo
    u16* ah   = xh;                            // alias: x_t dead after proj GEMM

    prep<<<1088, 256, 0, stream>>>(wq, wo, fp, wqh, woh, wol, trig);
    conv_xt<<<dim3(F_ / 64, W_ / 64, BC_), 256, 0, stream>>>(x, xh);

    gemm3<0><<<dim3(F_ / 128, W_ / 128, BC_), 256, 0, stream>>>(
        wqh, nullptr, xh, nullptr, vbuf, qbuf, nullptr, trig);

    attn3<<<dim3(W_ / 128, NH_, BC_), 256, 0, stream>>>(qbuf, vbuf, ah, al);

    gemm3<1><<<dim3(F_ / 128, W_ / 128, BC_), 256, 0, stream>>>(
        woh, wol, ah, al, nullptr, nullptr, out, nullptr);
}